// Round 9
// baseline (230.225 us; speedup 1.0000x reference)
//
#include <hip/hip_runtime.h>
#include <stdint.h>

// SynapticSNN — R15: re-fuse GEMM1+rec with the R14-proven 128x64 tile.
// R14 post-mortem: split passed (226us) but loses to fused R0 (212) — same-
// stream kernels serialize, so split pays gemm-issue + rec-issue sequentially
// (172us) while fusion overlaps phases across co-resident blocks (158us) and
// skips the 64MB cur1 round-trip. R14 proved the 128x64/8x4 gemm chain is
// bitwise-safe; rec stays scalar __f*_rn (R13: v_pk_*_f32 BANNED — not
// bitwise == scalar; R8-R10: MFMA GEMM1 BANNED — any k-reorder flips spikes
// to absmax 0.0859). This kernel = R14 gemm + R0-style rec epilogue (32
// outputs, 4 groups of 8) + LDS stride 132/68 -> 129/65 (stride===1 mod 32:
// staging-write banks 4sc+e+sr <=2-way = free, vs 4-way/6.3e6 conflicts at
// R0; reads broadcast/2-way — pure layout, zero numerics).
// k2/k3 = R0 proven. R11 reminder: watch FETCH/WRITE for spill signature.

typedef __attribute__((ext_vector_type(8))) short short8;
typedef __attribute__((ext_vector_type(4))) float floatx4;

#define NSTEPS 100

static __device__ __forceinline__ uint32_t f2bf2(float lo, float hi) {
  union { float f; uint32_t u; } a, b; a.f = lo; b.f = hi;
  uint32_t x = (a.u + 0x7FFFu + ((a.u >> 16) & 1u)) >> 16;
  uint32_t y = (b.u + 0x7FFFu + ((b.u >> 16) & 1u)) & 0xFFFF0000u;
  return x | y;
}

// ---------------------------------------------------------------------------
// Kernel 1 (R15): GEMM1 128Mx64N tile, 8x4/thread, BK=32, register-prefetch
// double buffer + fused exact recurrence epilogue. Grid (32,32)=1024 blocks
// (4/CU). Per-output accumulation: k ascending, single fmac chain — bitwise
// identical to R0/R12/R14 passing kernels. spk (bf16 {0,1}) -> ws.
// ---------------------------------------------------------------------------
__global__ __launch_bounds__(256, 4) void snn_k1(
    const float* __restrict__ X, const float* __restrict__ W1,
    const float* __restrict__ b1, const float* __restrict__ betap,
    uint16_t* __restrict__ spk)
{
  __shared__ __align__(16) float As[32 * 129];   // [k][m 128+1] stride===1 mod 32
  __shared__ __align__(16) float Bs[32 * 65];    // [k][n 64+1]
  const int tid = threadIdx.x;
  const int bn  = blockIdx.x * 64;   // hidden cols
  const int bm  = blockIdx.y * 128;  // batch rows
  const int ty  = tid >> 4;          // 0..15 -> rows ty*8
  const int tx  = tid & 15;          // 0..15 -> cols tx*4
  const int sr  = tid >> 3;          // staging row 0..31
  const int sc  = tid & 7;           // staging k-group (4 floats)

  float acc[8][4] = {};

  float4 xa[4], wa[2];
  #pragma unroll
  for (int h = 0; h < 4; ++h)
    xa[h] = *(const float4*)(X + (size_t)(bm + h * 32 + sr) * 256 + sc * 4);
  #pragma unroll
  for (int h = 0; h < 2; ++h)
    wa[h] = *(const float4*)(W1 + (size_t)(bn + h * 32 + sr) * 256 + sc * 4);

  #pragma unroll 1
  for (int k0 = 0; k0 < 256; k0 += 32) {
    #pragma unroll
    for (int h = 0; h < 4; ++h) {
      const int r = h * 32 + sr;
      As[(sc * 4 + 0) * 129 + r] = xa[h].x;
      As[(sc * 4 + 1) * 129 + r] = xa[h].y;
      As[(sc * 4 + 2) * 129 + r] = xa[h].z;
      As[(sc * 4 + 3) * 129 + r] = xa[h].w;
    }
    #pragma unroll
    for (int h = 0; h < 2; ++h) {
      const int r = h * 32 + sr;
      Bs[(sc * 4 + 0) * 65 + r] = wa[h].x;
      Bs[(sc * 4 + 1) * 65 + r] = wa[h].y;
      Bs[(sc * 4 + 2) * 65 + r] = wa[h].z;
      Bs[(sc * 4 + 3) * 65 + r] = wa[h].w;
    }
    __syncthreads();

    if (k0 < 224) {
      const int kn = k0 + 32;
      #pragma unroll
      for (int h = 0; h < 4; ++h)
        xa[h] = *(const float4*)(X + (size_t)(bm + h * 32 + sr) * 256 + kn + sc * 4);
      #pragma unroll
      for (int h = 0; h < 2; ++h)
        wa[h] = *(const float4*)(W1 + (size_t)(bn + h * 32 + sr) * 256 + kn + sc * 4);
    }

    #pragma unroll
    for (int kk = 0; kk < 32; ++kk) {
      const float4 a0 = *(const float4*)(As + kk * 129 + ty * 8);
      const float4 a1 = *(const float4*)(As + kk * 129 + ty * 8 + 4);
      const float4 b0 = *(const float4*)(Bs + kk * 65 + tx * 4);
      const float av[8] = {a0.x, a0.y, a0.z, a0.w, a1.x, a1.y, a1.z, a1.w};
      const float bv[4] = {b0.x, b0.y, b0.z, b0.w};
      #pragma unroll
      for (int i = 0; i < 8; ++i)
        #pragma unroll
        for (int j = 0; j < 4; ++j)
          acc[i][j] += av[i] * bv[j];
    }
    __syncthreads();
  }

  float beta = betap[0];
  beta = fminf(fmaxf(beta, 0.0f), 1.0f);
  float bias[4];
  #pragma unroll
  for (int j = 0; j < 4; ++j) bias[j] = b1[bn + tx * 4 + j];

  float cc[32];
  #pragma unroll
  for (int i = 0; i < 8; ++i)
    #pragma unroll
    for (int j = 0; j < 4; ++j)
      cc[i * 4 + j] = acc[i][j] + bias[j];

  // Recurrence: 4 groups of 8 elems (rows 2g,2g+1 x 4 cols). Exact reference
  // op order per element: reset from pre-update mem; no FMA contraction.
  #pragma unroll
  for (int g = 0; g < 4; ++g) {
    float syn[8], mem[8];
    #pragma unroll
    for (int e = 0; e < 8; ++e) { syn[e] = 0.0f; mem[e] = 0.0f; }

    #pragma unroll 1
    for (int t = 0; t < NSTEPS; ++t) {
      #pragma unroll
      for (int e = 0; e < 8; ++e) {
        const float rst = (mem[e] > 1.0f) ? 1.0f : 0.0f;
        syn[e] = __fadd_rn(__fmul_rn(0.9f, syn[e]), cc[g * 8 + e]);
        mem[e] = __fsub_rn(__fadd_rn(__fmul_rn(beta, mem[e]), syn[e]), rst);
      }
    }

    #pragma unroll
    for (int rr = 0; rr < 2; ++rr) {
      const int row = bm + ty * 8 + g * 2 + rr;
      ushort4 o;
      o.x = (mem[rr * 4 + 0] > 1.0f) ? (uint16_t)0x3F80u : (uint16_t)0u;
      o.y = (mem[rr * 4 + 1] > 1.0f) ? (uint16_t)0x3F80u : (uint16_t)0u;
      o.z = (mem[rr * 4 + 2] > 1.0f) ? (uint16_t)0x3F80u : (uint16_t)0u;
      o.w = (mem[rr * 4 + 3] > 1.0f) ? (uint16_t)0x3F80u : (uint16_t)0u;
      *(ushort4*)(spk + (size_t)row * 2048 + bn + tx * 4) = o;
    }
  }
}

// ---------------------------------------------------------------------------
// Kernel 2 (R0 proven): spk[4096,2048](bf16) @ W2[128,2048]^T via 16x16x32
// bf16 MFMA. 128m x 128n tiles, split-K=8. part[kc][4096][128] fp32 -> ws.
// ---------------------------------------------------------------------------
#define PS 72

__global__ __launch_bounds__(256) void snn_k2(
    const uint16_t* __restrict__ spk, const float* __restrict__ W2,
    float* __restrict__ part)
{
  __shared__ short As[128 * PS];
  __shared__ short Bs[128 * PS];
  const int tid  = threadIdx.x;
  const int lane = tid & 63;
  const int w    = tid >> 6;
  const int wm   = (w >> 1) * 64;
  const int wn   = (w & 1) * 64;
  const int bm   = blockIdx.x * 128;
  const int kc   = blockIdx.y;          // K chunk of 256

  floatx4 acc[4][4] = {};

  #pragma unroll 1
  for (int kk = 0; kk < 4; ++kk) {
    const int k0 = kc * 256 + kk * 64;
    #pragma unroll
    for (int p = 0; p < 4; ++p) {
      const int u = p * 256 + tid;
      const int r = u >> 3, c = u & 7;
      const int4 va = *(const int4*)(spk + (size_t)(bm + r) * 2048 + k0 + c * 8);
      *(int4*)(As + r * PS + c * 8) = va;
    }
    #pragma unroll
    for (int p = 0; p < 4; ++p) {
      const int u = p * 256 + tid;
      const int n = u >> 3, c = u & 7;
      const float* wp = W2 + (size_t)n * 2048 + k0 + c * 8;
      const float4 w0 = *(const float4*)(wp);
      const float4 w1 = *(const float4*)(wp + 4);
      int4 pk;
      pk.x = (int)f2bf2(w0.x, w0.y);
      pk.y = (int)f2bf2(w0.z, w0.w);
      pk.z = (int)f2bf2(w1.x, w1.y);
      pk.w = (int)f2bf2(w1.z, w1.w);
      *(int4*)(Bs + n * PS + c * 8) = pk;
    }
    __syncthreads();

    #pragma unroll
    for (int ks = 0; ks < 2; ++ks) {
      const int kb = ks * 4 + (lane >> 4);
      const int fe = lane & 15;
      short8 a8[4], b8[4];
      #pragma unroll
      for (int tm = 0; tm < 4; ++tm)
        a8[tm] = *(const short8*)(As + (wm + tm * 16 + fe) * PS + kb * 8);
      #pragma unroll
      for (int tn = 0; tn < 4; ++tn)
        b8[tn] = *(const short8*)(Bs + (wn + tn * 16 + fe) * PS + kb * 8);
      #pragma unroll
      for (int tm = 0; tm < 4; ++tm)
        #pragma unroll
        for (int tn = 0; tn < 4; ++tn)
          acc[tm][tn] = __builtin_amdgcn_mfma_f32_16x16x32_bf16(
              a8[tm], b8[tn], acc[tm][tn], 0, 0, 0);
    }
    __syncthreads();
  }

  const int fe = lane & 15;
  const int fr = (lane >> 4) * 4;
  #pragma unroll
  for (int tm = 0; tm < 4; ++tm)
    #pragma unroll
    for (int tn = 0; tn < 4; ++tn)
      #pragma unroll
      for (int r = 0; r < 4; ++r) {
        const int row = bm + wm + tm * 16 + fr + r;
        const int col = wn + tn * 16 + fe;
        part[((size_t)kc * 4096 + row) * 128 + col] = acc[tm][tn][r];
      }
}

// ---------------------------------------------------------------------------
// Kernel 3 (R0 proven): out[m][n] = sum_kc part[kc][m][n] + b2[n]
// ---------------------------------------------------------------------------
__global__ __launch_bounds__(256) void snn_k3(
    const float* __restrict__ part, const float* __restrict__ b2,
    float* __restrict__ out)
{
  const int idx = blockIdx.x * 256 + threadIdx.x;
  const int m = idx >> 5;
  const int c = (idx & 31) << 2;
  float s0 = 0.f, s1 = 0.f, s2 = 0.f, s3 = 0.f;
  #pragma unroll
  for (int kc = 0; kc < 8; ++kc) {
    const float4 p = *(const float4*)(part + ((size_t)kc * 4096 + m) * 128 + c);
    s0 += p.x; s1 += p.y; s2 += p.z; s3 += p.w;
  }
  float4 o;
  o.x = s0 + b2[c + 0];
  o.y = s1 + b2[c + 1];
  o.z = s2 + b2[c + 2];
  o.w = s3 + b2[c + 3];
  *(float4*)(out + (size_t)m * 128 + c) = o;
}

extern "C" void kernel_launch(void* const* d_in, const int* in_sizes, int n_in,
                              void* d_out, int out_size, void* d_ws, size_t ws_size,
                              hipStream_t stream) {
  const float* X    = (const float*)d_in[0];  // [4096,256]
  const float* W1   = (const float*)d_in[1];  // [2048,256]
  const float* b1   = (const float*)d_in[2];  // [2048]
  const float* W2   = (const float*)d_in[3];  // [128,2048]
  const float* b2   = (const float*)d_in[4];  // [128]
  const float* beta = (const float*)d_in[5];  // scalar
  float* out = (float*)d_out;                 // [4096,128] fp32

  uint16_t* spk = (uint16_t*)d_ws;                                 // 16 MiB
  float* part   = (float*)((char*)d_ws + (size_t)4096 * 2048 * 2); // 16 MiB

  snn_k1<<<dim3(32, 32), 256, 0, stream>>>(X, W1, b1, beta, spk);
  snn_k2<<<dim3(32, 8), 256, 0, stream>>>(spk, W2, part);
  snn_k3<<<512, 256, 0, stream>>>(part, b2, out);
}